// Round 14
// baseline (55.351 us; speedup 1.0000x reference)
//
#include <hip/hip_runtime.h>
#include <hip/hip_bf16.h>

typedef unsigned short u16;
typedef __attribute__((ext_vector_type(8))) __bf16 bf16x8;
typedef __attribute__((ext_vector_type(16))) float f32x16;

#define B_SZ 4096
#define D_SZ 1024
#define MARGIN 0.2f

__device__ __forceinline__ u16 f2bf(float x) {
  __hip_bfloat16 h = __float2bfloat16(x);
  u16 r; __builtin_memcpy(&r, &h, 2); return r;
}

// ---------------- normalize + cast to bf16 + diag (wave-per-row) ----------
// r13 kernel unchanged (~8.6us, near the 7.6us HBM floor).
__global__ __launch_bounds__(256) void norm_diag_kernel(
    const float* __restrict__ im, const float* __restrict__ tx,
    u16* __restrict__ imn, u16* __restrict__ txn,
    float* __restrict__ diag, float* __restrict__ loss) {
  const int l = threadIdx.x & 63;
  const int row = blockIdx.x * 4 + (threadIdx.x >> 6);
  if (blockIdx.x == 0 && threadIdx.x == 0) *loss = 0.f;
  const size_t base = (size_t)row * D_SZ;
  const float4* pi4 = reinterpret_cast<const float4*>(im + base);
  const float4* pt4 = reinterpret_cast<const float4*>(tx + base);
  float4 vi[4], vt[4];
#pragma unroll
  for (int k = 0; k < 4; k++) { vi[k] = pi4[l + 64 * k]; vt[k] = pt4[l + 64 * k]; }
  float ssi = 0.f, sst = 0.f, dot = 0.f;
#pragma unroll
  for (int k = 0; k < 4; k++) {
    ssi += vi[k].x * vi[k].x + vi[k].y * vi[k].y + vi[k].z * vi[k].z + vi[k].w * vi[k].w;
    sst += vt[k].x * vt[k].x + vt[k].y * vt[k].y + vt[k].z * vt[k].z + vt[k].w * vt[k].w;
    dot += vi[k].x * vt[k].x + vi[k].y * vt[k].y + vi[k].z * vt[k].z + vi[k].w * vt[k].w;
  }
#pragma unroll
  for (int off = 32; off > 0; off >>= 1) {
    ssi += __shfl_xor(ssi, off, 64);
    sst += __shfl_xor(sst, off, 64);
    dot += __shfl_xor(dot, off, 64);
  }
  const float si = 1.0f / fmaxf(sqrtf(ssi), 1e-12f);
  const float st = 1.0f / fmaxf(sqrtf(sst), 1e-12f);
#pragma unroll
  for (int k = 0; k < 4; k++) {
    u16 oi[4] = { f2bf(vi[k].x * si), f2bf(vi[k].y * si),
                  f2bf(vi[k].z * si), f2bf(vi[k].w * si) };
    u16 ot[4] = { f2bf(vt[k].x * st), f2bf(vt[k].y * st),
                  f2bf(vt[k].z * st), f2bf(vt[k].w * st) };
    ushort4 pi, pt; __builtin_memcpy(&pi, oi, 8); __builtin_memcpy(&pt, ot, 8);
    reinterpret_cast<ushort4*>(imn + base)[l + 64 * k] = pi;
    reinterpret_cast<ushort4*>(txn + base)[l + 64 * k] = pt;
  }
  if (l == 0) diag[row] = dot * si * st;
}

// ---------------- 256x256 GEMM, 16 waves, BK=64, fused hinge loss ----------
// Round-14: r12 structure (41.4us, 0 conflicts, 1 atomic/block) with MFMA
// swapped 16x16x32 -> 32x32x16 (m119: 2495 vs 2176 TF; 16 mfma x 8.07cyc =
// 129 vs 32 x 4.85 = 155 cyc/wave/K-tile). Wave = 64x64 = 2x2 tiles of 32^2,
// 4 ks-steps of K=16. LDS layout/staging/swizzle identical; read pattern
// re-derived: row = base+(l&31), slot = (ks*2+(l>>5)) ^ (l&7) -> same 8-way
// slot-group banking as the measured-zero-conflict r12 pattern.
// C/D mapping (m74/m101): col=lane&31, row=(reg&3)+8*(reg>>2)+4*(lane>>5).
__device__ __forceinline__ void gload_lds16(const u16* g, u16* l) {
  __builtin_amdgcn_global_load_lds((__attribute__((address_space(1))) void*)g,
                                   (__attribute__((address_space(3))) void*)l,
                                   16, 0, 0);
}

__global__ __launch_bounds__(1024, 4) void gemm_loss_kernel(
    const u16* __restrict__ A,   // imn [4096][1024]
    const u16* __restrict__ Bt,  // txn [4096][1024]
    const float* __restrict__ diag,
    float* __restrict__ sim,     // d_out+1, row-major [4096][4096]
    float* __restrict__ loss) {
  __shared__ u16 sm[65536];      // 2 bufs x 4 regions x 8192 u16 = 128 KiB

  const int tid = threadIdx.x;
  const int l = tid & 63;
  const int w = tid >> 6;        // wave 0..15
  const int wr = w >> 2;         // 0..3  M quarter
  const int wc = w & 3;          // 0..3  N quarter
  const int l31 = l & 31;
  const int lh = l >> 5;         // 0..1
  const int l7 = l & 7;

  // XCD-aware bijective swizzle: 256 blocks, 8 XCDs, 32 consecutive per XCD.
  const int bid = blockIdx.x;
  const int s = (bid & 7) * 32 + (bid >> 3);
  const int tm = (s >> 4) * 256;
  const int tn = (s & 15) * 256;

  f32x16 acc[2][2] = {};

  // ---- staging: wave w stages rows 8w..8w+8 of each region (unchanged) ----
  const int l3 = l >> 3;
  const int cb = l7 ^ l3;                  // involution with read swizzle
  const int rho = w * 8 + l3;              // 0..127
  const u16* pR[4];
  pR[0] = A  + (size_t)(tm + rho)       * D_SZ + cb * 8;   // A0
  pR[1] = A  + (size_t)(tm + 128 + rho) * D_SZ + cb * 8;   // A1
  pR[2] = Bt + (size_t)(tn + rho)       * D_SZ + cb * 8;   // B0
  pR[3] = Bt + (size_t)(tn + 128 + rho) * D_SZ + cb * 8;   // B1

  // ---- read offsets for 32x32x16 fragments ----
  // A m-tile mt: region A(wr>>1), row = (wr&1)*64 + mt*32 + l31
  // B n-tile nt: region B(wc>>1), row = (wc&1)*64 + nt*32 + l31
  // k-slot for ks: slot' = (ks*2 + lh) ^ l7; elem = row*64 + slot'*8
  const int aReg = wr >> 1;
  const int bReg = 2 + (wc >> 1);
  int aRow[2], bRow[2], slx[4];
#pragma unroll
  for (int mt = 0; mt < 2; mt++) aRow[mt] = ((wr & 1) * 64 + mt * 32 + l31) * 64;
#pragma unroll
  for (int nt = 0; nt < 2; nt++) bRow[nt] = ((wc & 1) * 64 + nt * 32 + l31) * 64;
#pragma unroll
  for (int ks = 0; ks < 4; ks++) slx[ks] = ((ks * 2 + lh) ^ l7) * 8;

  // ---- prologue: stage K-tile 0 into buf 0 ----
#pragma unroll
  for (int c = 0; c < 4; c++)
    gload_lds16(pR[c], sm + c * 8192 + w * 512);
  __syncthreads();

#pragma unroll 1
  for (int t = 0; t < 16; ++t) {
    const int buf = t & 1;
    if (t + 1 < 16) {
      const int nb = buf ^ 1;
      const int ko = (t + 1) * 64;
#pragma unroll
      for (int c = 0; c < 4; c++)
        gload_lds16(pR[c] + ko, sm + (nb * 4 + c) * 8192 + w * 512);
    }
    const u16* Ab = sm + (buf * 4 + aReg) * 8192;
    const u16* Bb = sm + (buf * 4 + bReg) * 8192;
#pragma unroll
    for (int ks = 0; ks < 4; ks++) {
      bf16x8 aF[2], bF[2];
#pragma unroll
      for (int mt = 0; mt < 2; mt++) aF[mt] = *(const bf16x8*)&Ab[aRow[mt] + slx[ks]];
#pragma unroll
      for (int nt = 0; nt < 2; nt++) bF[nt] = *(const bf16x8*)&Bb[bRow[nt] + slx[ks]];
#pragma unroll
      for (int mt = 0; mt < 2; mt++)
#pragma unroll
        for (int nt = 0; nt < 2; nt++)
          acc[mt][nt] = __builtin_amdgcn_mfma_f32_32x32x16_bf16(
              aF[mt], bF[nt], acc[mt][nt], 0, 0, 0);
    }
    __syncthreads();   // drains stage(t+1) + protects buf for stage(t+2)
  }

  // ---- epilogue: sim stores + fused hinge loss ----
  // C/D: col = l31 (+tile base), row = (j&3) + 8*(j>>2) + 4*lh (+tile base)
  float dcs[2];
#pragma unroll
  for (int nt = 0; nt < 2; nt++) dcs[nt] = diag[tn + wc * 64 + nt * 32 + l31];
  float lsum = 0.f;
#pragma unroll
  for (int mt = 0; mt < 2; mt++) {
#pragma unroll
    for (int j = 0; j < 16; j++) {
      const int r = tm + wr * 64 + mt * 32 + (j & 3) + 8 * (j >> 2) + 4 * lh;
      const float dr = diag[r];
#pragma unroll
      for (int nt = 0; nt < 2; nt++) {
        const int c = tn + wc * 64 + nt * 32 + l31;
        const float s_ = acc[mt][nt][j];
        sim[(size_t)r * B_SZ + c] = s_;
        if (r != c)
          lsum += fmaxf(MARGIN + s_ - dr, 0.f) + fmaxf(MARGIN + s_ - dcs[nt], 0.f);
      }
    }
  }
#pragma unroll
  for (int off = 32; off > 0; off >>= 1) lsum += __shfl_down(lsum, off, 64);

  // block-level reduction: ONE atomic per block (256 total).
  float* wsum = (float*)sm;      // LDS reuse; K-loop fully done
  if (l == 0) wsum[w] = lsum;
  __syncthreads();
  if (tid == 0) {
    float tot = 0.f;
#pragma unroll
    for (int i = 0; i < 16; i++) tot += wsum[i];
    atomicAdd(loss, tot);
  }
}

extern "C" void kernel_launch(void* const* d_in, const int* in_sizes, int n_in,
                              void* d_out, int out_size, void* d_ws, size_t ws_size,
                              hipStream_t stream) {
  const float* im = (const float*)d_in[0];
  const float* tx = (const float*)d_in[1];
  float* out = (float*)d_out;
  float* loss = out;        // output 0: scalar total_loss
  float* sim = out + 1;     // output 1: [4096][4096]

  u16* imn = (u16*)d_ws;
  u16* txn = imn + (size_t)B_SZ * D_SZ;
  float* diag = (float*)(txn + (size_t)B_SZ * D_SZ);

  norm_diag_kernel<<<B_SZ / 4, 256, 0, stream>>>(im, tx, imn, txn, diag, loss);
  gemm_loss_kernel<<<(B_SZ / 256) * (B_SZ / 256), 1024, 0, stream>>>(imn, txn, diag, sim, loss);
}

// Round 15
// 51.800 us; speedup vs baseline: 1.0686x; 1.0686x over previous
//
#include <hip/hip_runtime.h>
#include <hip/hip_bf16.h>

typedef unsigned short u16;
typedef __attribute__((ext_vector_type(8))) __bf16 bf16x8;
typedef __attribute__((ext_vector_type(4))) float f32x4;

#define B_SZ 4096
#define D_SZ 1024
#define MARGIN 0.2f

__device__ __forceinline__ u16 f2bf(float x) {
  __hip_bfloat16 h = __float2bfloat16(x);
  u16 r; __builtin_memcpy(&r, &h, 2); return r;
}

// ---------------- normalize + cast to bf16 + diag (wave-per-row) ----------
// One wave per row; 3 shfl_xor butterfly chains, no LDS/barrier; zeroes loss.
// ~8.6us vs 7.6us HBM floor (r13-measured).
__global__ __launch_bounds__(256) void norm_diag_kernel(
    const float* __restrict__ im, const float* __restrict__ tx,
    u16* __restrict__ imn, u16* __restrict__ txn,
    float* __restrict__ diag, float* __restrict__ loss) {
  const int l = threadIdx.x & 63;
  const int row = blockIdx.x * 4 + (threadIdx.x >> 6);
  if (blockIdx.x == 0 && threadIdx.x == 0) *loss = 0.f;
  const size_t base = (size_t)row * D_SZ;
  const float4* pi4 = reinterpret_cast<const float4*>(im + base);
  const float4* pt4 = reinterpret_cast<const float4*>(tx + base);
  float4 vi[4], vt[4];
#pragma unroll
  for (int k = 0; k < 4; k++) { vi[k] = pi4[l + 64 * k]; vt[k] = pt4[l + 64 * k]; }
  float ssi = 0.f, sst = 0.f, dot = 0.f;
#pragma unroll
  for (int k = 0; k < 4; k++) {
    ssi += vi[k].x * vi[k].x + vi[k].y * vi[k].y + vi[k].z * vi[k].z + vi[k].w * vi[k].w;
    sst += vt[k].x * vt[k].x + vt[k].y * vt[k].y + vt[k].z * vt[k].z + vt[k].w * vt[k].w;
    dot += vi[k].x * vt[k].x + vi[k].y * vt[k].y + vi[k].z * vt[k].z + vi[k].w * vt[k].w;
  }
#pragma unroll
  for (int off = 32; off > 0; off >>= 1) {
    ssi += __shfl_xor(ssi, off, 64);
    sst += __shfl_xor(sst, off, 64);
    dot += __shfl_xor(dot, off, 64);
  }
  const float si = 1.0f / fmaxf(sqrtf(ssi), 1e-12f);
  const float st = 1.0f / fmaxf(sqrtf(sst), 1e-12f);
#pragma unroll
  for (int k = 0; k < 4; k++) {
    u16 oi[4] = { f2bf(vi[k].x * si), f2bf(vi[k].y * si),
                  f2bf(vi[k].z * si), f2bf(vi[k].w * si) };
    u16 ot[4] = { f2bf(vt[k].x * st), f2bf(vt[k].y * st),
                  f2bf(vt[k].z * st), f2bf(vt[k].w * st) };
    ushort4 pi, pt; __builtin_memcpy(&pi, oi, 8); __builtin_memcpy(&pt, ot, 8);
    reinterpret_cast<ushort4*>(imn + base)[l + 64 * k] = pi;
    reinterpret_cast<ushort4*>(txn + base)[l + 64 * k] = pt;
  }
  if (l == 0) diag[row] = dot * si * st;
}

// ---------------- 256x256 GEMM, 16 waves, BK=64, fused hinge loss ----------
// FINAL (r12/r13-proven, 41.4us): 16x16x32 MFMA, 16 waves as 4Mx4N (64x64
// per wave), one barrier per K-tile, dbuf 128 KiB LDS, zero-conflict XOR
// involution layout (16 rows/read x 8-slot XOR = 2 lanes/bank-group = free;
// NOTE: 32x32 MFMA is structurally 4-way-conflicted at this pitch - r14),
// XCD-swizzled grid, __launch_bounds__(1024,4) -> 4 waves/SIMD resident,
// ONE atomicAdd per block (4096 same-address wave-atomics cost 47us - r11).
__device__ __forceinline__ void gload_lds16(const u16* g, u16* l) {
  __builtin_amdgcn_global_load_lds((__attribute__((address_space(1))) void*)g,
                                   (__attribute__((address_space(3))) void*)l,
                                   16, 0, 0);
}

__global__ __launch_bounds__(1024, 4) void gemm_loss_kernel(
    const u16* __restrict__ A,   // imn [4096][1024]
    const u16* __restrict__ Bt,  // txn [4096][1024]
    const float* __restrict__ diag,
    float* __restrict__ sim,     // d_out+1, row-major [4096][4096]
    float* __restrict__ loss) {
  __shared__ u16 sm[65536];      // 2 bufs x 4 regions x 8192 u16 = 128 KiB

  const int tid = threadIdx.x;
  const int l = tid & 63;
  const int w = tid >> 6;        // wave 0..15
  const int wr = w >> 2;         // 0..3  M quarter
  const int wc = w & 3;          // 0..3  N quarter
  const int ar = l & 15;
  const int arh = l >> 4;

  // XCD-aware bijective swizzle: 256 blocks, 8 XCDs, 32 consecutive per XCD.
  const int bid = blockIdx.x;
  const int s = (bid & 7) * 32 + (bid >> 3);
  const int tm = (s >> 4) * 256;
  const int tn = (s & 15) * 256;

  f32x4 acc[4][4] = {};

  // ---- staging: wave w stages rows 8w..8w+8 of each region ----
  const int l3 = l >> 3;
  const int cb = (l & 7) ^ l3;             // involution with read swizzle
  const int rho = w * 8 + l3;              // 0..127
  const u16* pR[4];
  pR[0] = A  + (size_t)(tm + rho)       * D_SZ + cb * 8;   // A0
  pR[1] = A  + (size_t)(tm + 128 + rho) * D_SZ + cb * 8;   // A1
  pR[2] = Bt + (size_t)(tn + rho)       * D_SZ + cb * 8;   // B0
  pR[3] = Bt + (size_t)(tn + 128 + rho) * D_SZ + cb * 8;   // B1

  // ---- read offsets (stored slot = (ks*4+arh) ^ (row&7); row&7 == ar&7) ----
  const int sl0 = (arh ^ (ar & 7)) * 8;
  const int sl1 = ((4 + arh) ^ (ar & 7)) * 8;
  const int aOfs = ((wr & 1) * 64 + ar) * 64;   // within region A(wr>>1)
  const int bOfs = ((wc & 1) * 64 + ar) * 64;   // within region B(wc>>1)
  const int aReg = wr >> 1;                     // 0..1
  const int bReg = 2 + (wc >> 1);               // 2..3

  // ---- prologue: stage K-tile 0 into buf 0 ----
#pragma unroll
  for (int c = 0; c < 4; c++)
    gload_lds16(pR[c], sm + c * 8192 + w * 512);
  __syncthreads();

#pragma unroll 1
  for (int t = 0; t < 16; ++t) {
    const int buf = t & 1;
    if (t + 1 < 16) {
      const int nb = buf ^ 1;
      const int ko = (t + 1) * 64;
#pragma unroll
      for (int c = 0; c < 4; c++)
        gload_lds16(pR[c] + ko, sm + (nb * 4 + c) * 8192 + w * 512);
    }
    const u16* Ab = sm + (buf * 4 + aReg) * 8192 + aOfs;
    const u16* Bb = sm + (buf * 4 + bReg) * 8192 + bOfs;
    {
      bf16x8 af[4], bfr[4];
#pragma unroll
      for (int m = 0; m < 4; m++) af[m] = *(const bf16x8*)&Ab[m * 1024 + sl0];
#pragma unroll
      for (int n = 0; n < 4; n++) bfr[n] = *(const bf16x8*)&Bb[n * 1024 + sl0];
#pragma unroll
      for (int m = 0; m < 4; m++)
#pragma unroll
        for (int n = 0; n < 4; n++)
          acc[m][n] = __builtin_amdgcn_mfma_f32_16x16x32_bf16(af[m], bfr[n], acc[m][n], 0, 0, 0);
    }
    {
      bf16x8 af[4], bfr[4];
#pragma unroll
      for (int m = 0; m < 4; m++) af[m] = *(const bf16x8*)&Ab[m * 1024 + sl1];
#pragma unroll
      for (int n = 0; n < 4; n++) bfr[n] = *(const bf16x8*)&Bb[n * 1024 + sl1];
#pragma unroll
      for (int m = 0; m < 4; m++)
#pragma unroll
        for (int n = 0; n < 4; n++)
          acc[m][n] = __builtin_amdgcn_mfma_f32_16x16x32_bf16(af[m], bfr[n], acc[m][n], 0, 0, 0);
    }
    __syncthreads();   // drains stage(t+1) + protects buf for stage(t+2)
  }

  // ---- epilogue: sim stores + fused hinge loss ----
  float dcs[4];
#pragma unroll
  for (int n = 0; n < 4; n++) dcs[n] = diag[tn + wc * 64 + n * 16 + ar];
  float lsum = 0.f;
#pragma unroll
  for (int m = 0; m < 4; m++) {
#pragma unroll
    for (int i = 0; i < 4; i++) {
      const int r = tm + wr * 64 + m * 16 + arh * 4 + i;
      const float dr = diag[r];
#pragma unroll
      for (int n = 0; n < 4; n++) {
        const int c = tn + wc * 64 + n * 16 + ar;
        const float s_ = acc[m][n][i];
        sim[(size_t)r * B_SZ + c] = s_;
        if (r != c)
          lsum += fmaxf(MARGIN + s_ - dr, 0.f) + fmaxf(MARGIN + s_ - dcs[n], 0.f);
      }
    }
  }
#pragma unroll
  for (int off = 32; off > 0; off >>= 1) lsum += __shfl_down(lsum, off, 64);

  // block-level reduction: ONE atomic per block (256 total).
  float* wsum = (float*)sm;      // LDS reuse; K-loop fully done
  if (l == 0) wsum[w] = lsum;
  __syncthreads();
  if (tid == 0) {
    float tot = 0.f;
#pragma unroll
    for (int i = 0; i < 16; i++) tot += wsum[i];
    atomicAdd(loss, tot);
  }
}

extern "C" void kernel_launch(void* const* d_in, const int* in_sizes, int n_in,
                              void* d_out, int out_size, void* d_ws, size_t ws_size,
                              hipStream_t stream) {
  const float* im = (const float*)d_in[0];
  const float* tx = (const float*)d_in[1];
  float* out = (float*)d_out;
  float* loss = out;        // output 0: scalar total_loss
  float* sim = out + 1;     // output 1: [4096][4096]

  u16* imn = (u16*)d_ws;
  u16* txn = imn + (size_t)B_SZ * D_SZ;
  float* diag = (float*)(txn + (size_t)B_SZ * D_SZ);

  norm_diag_kernel<<<B_SZ / 4, 256, 0, stream>>>(im, tx, imn, txn, diag, loss);
  gemm_loss_kernel<<<(B_SZ / 256) * (B_SZ / 256), 1024, 0, stream>>>(imn, txn, diag, sim, loss);
}